// Round 5
// baseline (6624.005 us; speedup 1.0000x reference)
//
#include <hip/hip_runtime.h>

#define B     16
#define TENC  128
#define TDEC  100
#define IND   256
#define HID   256
#define OD    400
#define MD    80
#define LBUF  17
#define BD    336
#define BS    5712
#define BH    571
#define MH    40
#define NSLOT 117

// persistent-scan geometry
#define NBULK 195          // 15 kc x 13 ct
#define NFR   13           // fresh/h1 col-tile blocks (4 pq + 9 S)
#define NU    14           // u-GEMV blocks (24 dd each)
#define NCONS 16
#define NBLK  (NBULK + NFR + NU + NCONS)   // 238
#define KPT   45           // bulk k per kq slot (8*45=360)

// workspace layout (float offsets)
#define OFF_U    0                       // 117*16*336 = 628992
#define OFF_PA   628992                  // 16*128*256 = 524288
#define OFF_MEM  1153280                 // 100*16*80  = 128000
#define OFF_M    1281280                 // 17*336*400 = 2284800
#define OFF_CO   3566080                 // 400
#define OFF_P    3566480                 // 4*15*16*832 = 798720
#define OFF_W2T  4365200                 // 336*572 = 192192
#define OFF_FPQ  4557392                 // 16*256 = 4096
#define OFF_TOP  4561488                 // 16*336 = 5376
#define OFF_H1   4566864                 // 16*572 = 9152
#define OFF_FLG  4576016                 // 30400 ints

// flag int-offsets (lines of 16 ints per t)
#define FG_CONS  0          // words 0..13  (U blocks)
#define FG_PQF   1600       // words 0..3   (FR pq tiles)
#define FG_TOP   3200       // words 0..15  (consumers)
#define FG_H1    4800       // words 0..8   (FR S tiles)
#define FG_BULK  6400       // (t*15+kc)*16 + ct

#define RLX __ATOMIC_RELAXED
#define AGT __HIP_MEMORY_SCOPE_AGENT
#define SCLD(p)    __hip_atomic_load((p), RLX, AGT)
#define SCST(p,v)  __hip_atomic_store((p), (v), RLX, AGT)

__device__ __forceinline__ void wait_words(int* base, int n, int tid) {
    for (;;) {
        int p = 1;
        if (tid < n) p = (__hip_atomic_load(&base[tid], RLX, AGT) != 0);
        if (__syncthreads_count(p) == 512) return;
        __builtin_amdgcn_s_sleep(1);
    }
}

__global__ __launch_bounds__(256) void k_init(float* __restrict__ ws) {
    int i = blockIdx.x*256 + threadIdx.x;
    int nu = 17*B*BD;                        // 91392
    if (i < nu) ws[OFF_U + i] = 0.f;
    else if (i < nu + OD) ws[OFF_CO + (i - nu)] = 0.f;
    else if (i < nu + OD + 30400) ((int*)(ws + OFF_FLG))[i - nu - OD] = 0;
}

__global__ __launch_bounds__(256) void k_pa(const float* __restrict__ inputs,
        const float* __restrict__ wa, const float* __restrict__ ba,
        float* __restrict__ ws) {
    int bj = blockIdx.x;
    int tid = threadIdx.x;
    __shared__ float xin[IND];
    xin[tid] = inputs[bj*IND + tid];
    __syncthreads();
    float acc = ba[tid];
    #pragma unroll 4
    for (int i = 0; i < IND; i++) acc += xin[i]*wa[i*HID + tid];
    ws[OFF_PA + bj*HID + tid] = acc;
}

__global__ __launch_bounds__(128) void k_mem(const float* __restrict__ targets,
        const float* __restrict__ w1, const float* __restrict__ b1,
        const float* __restrict__ w2, const float* __restrict__ b2,
        float* __restrict__ ws) {
    int tb = blockIdx.x; int t = tb / B; int b = tb % B;
    int tid = threadIdx.x;
    __shared__ float xin[OD];
    __shared__ float hid[MH];
    for (int k = tid; k < OD; k += 128)
        xin[k] = (t == 0) ? 0.f : targets[(b*TDEC + (t-1))*OD + k];
    __syncthreads();
    if (tid < MH) {
        float a = b1[tid];
        for (int k = 0; k < OD; k++) a += xin[k]*w1[k*MH + tid];
        hid[tid] = fmaxf(a, 0.f);
    }
    __syncthreads();
    if (tid < MD) {
        float a = b2[tid];
        #pragma unroll
        for (int k = 0; k < MH; k++) a += hid[k]*w2[k*MD + tid];
        ws[OFF_MEM + (t*B + b)*MD + tid] = a;
    }
}

__global__ __launch_bounds__(256) void k_M(const float* __restrict__ scale_w,
        const float* __restrict__ out_w, float* __restrict__ ws) {
    int l  = blockIdx.x / 14;
    int d0 = (blockIdx.x % 14) * 24;
    int tid = threadIdx.x;
    __shared__ float sw[HID*24];
    for (int idx = tid; idx < HID*24; idx += 256) {
        int h = idx / 24, dl = idx % 24;
        sw[idx] = scale_w[h*BD + d0 + dl];
    }
    __syncthreads();
    int o0 = tid, o1 = tid + 256;
    bool v1 = o1 < OD;
    float a0[24], a1[24];
    #pragma unroll
    for (int i = 0; i < 24; i++) { a0[i] = 0.f; a1[i] = 0.f; }
    const float* owl = out_w + l*HID*OD;
    for (int h = 0; h < HID; h++) {
        float w0 = owl[h*OD + o0];
        float w1v = v1 ? owl[h*OD + o1] : 0.f;
        #pragma unroll
        for (int dl = 0; dl < 24; dl++) {
            float s = sw[h*24 + dl];
            a0[dl] += s*w0; a1[dl] += s*w1v;
        }
    }
    float* Mp = ws + OFF_M + l*BD*OD;
    for (int dl = 0; dl < 24; dl++) {
        Mp[(d0+dl)*OD + o0] = a0[dl];
        if (v1) Mp[(d0+dl)*OD + o1] = a1[dl];
    }
}

__global__ __launch_bounds__(256) void k_cout(const float* __restrict__ scale_b,
        const float* __restrict__ out_w, const float* __restrict__ out_b,
        float* __restrict__ ws) {
    int l = blockIdx.x; int tid = threadIdx.x;
    for (int p = 0; p < 2; p++) {
        int o = tid + p*256;
        if (o < OD) {
            float acc = (l == 0) ? out_b[o] : 0.f;
            for (int h = 0; h < HID; h++) acc += scale_b[h]*out_w[(l*HID + h)*OD + o];
            atomicAdd(&ws[OFF_CO + o], acc);
        }
    }
}

// w2T[dd][c] = bp_w2[c][dd], c padded to 572 with zeros
__global__ __launch_bounds__(256) void k_tr(const float* __restrict__ bp_w2,
        float* __restrict__ ws) {
    int i = blockIdx.x*256 + threadIdx.x;
    if (i < BD*572) {
        int dd = i / 572, c = i - 572*dd;
        ws[OFF_W2T + i] = (c < BH) ? bp_w2[c*BD + dd] : 0.f;
    }
}

// ---------------- persistent scan kernel ----------------
// Roles: [0,195) bulk (kc=bid/13, ct=bid%13)  k in [0,5376)
//        [195,208) FR (fresh u_{t-1} + top-row + h1)  col tile of 64
//        [208,222) U  (u = b2 + h1 @ w2T, 24 dd rows each)
//        [222,238) consumers (one per b): pq reduce + attention + top
// All cross-block data via relaxed agent atomics; flags are idempotent
// word-stores (value t+1) checked with __syncthreads_count — no RMW chains.
__global__ __launch_bounds__(512, 2) void k_scan(
        const float* __restrict__ inputs, const float* __restrict__ wq,
        const float* __restrict__ w1g, const float* __restrict__ att_bq,
        const float* __restrict__ bp_b1, const float* __restrict__ bp_b2,
        const float* __restrict__ att_v,
        float* __restrict__ ws, float* __restrict__ attns) {
    __shared__ __align__(16) char smem[57344];
    int bid = blockIdx.x, tid = threadIdx.x;
    int* flg = (int*)(ws + OFF_FLG);

    if (bid < NBULK) {
        // ================= BULK =================
        int kc = bid / 13, ct = bid % 13;
        float* ulds = (float*)smem;                  // 360*16 floats
        float* red  = (float*)(smem + 360*16*4);     // 8*1024 floats
        int cp = tid & 31, kq = (tid >> 5) & 7;
        bool comp = tid < 256;
        int g0 = ct*64 + cp, g1 = g0 + 32;
        float w0[KPT], w1r[KPT];
        #pragma unroll
        for (int g = 0; g < KPT; g++) { w0[g] = 0.f; w1r[g] = 0.f; }
        if (comp) {
            #pragma unroll
            for (int g = 0; g < KPT; g++) {
                int kg = kc*360 + kq*KPT + g;
                if (kg < 5376) {
                    int w = kg/336, d = kg - 336*w;
                    if (g0 < 256)      w0[g] = wq[((16-w)*336+d)*HID + g0];
                    else if (g0 < 827 && kg >= 336)
                                       w0[g] = w1g[((17-w)*336+d)*BH + (g0-256)];
                    if (g1 < 256)      w1r[g] = wq[((16-w)*336+d)*HID + g1];
                    else if (g1 < 827 && kg >= 336)
                                       w1r[g] = w1g[((17-w)*336+d)*BH + (g1-256)];
                }
            }
        }
        int khiv = kc*360 + 359; if (khiv > 5375) khiv = 5375;
        int whi = khiv / 336;
        for (int t = 0; t < TDEC; t++) {
            int s = t + whi - 17; int s2 = t - 4;
            if (s2 > s) s = s2;
            if (s >= 0) wait_words(flg + s*16, NU, tid);
            for (int e = tid; e < 5760; e += 512) {
                int b = e / 360, kl = e - b*360;
                int kg = kc*360 + kl;
                float v = 0.f;
                if (kg < 5376) {
                    int w = kg/336, d = kg - 336*w;
                    v = SCLD(&ws[OFF_U + ((t + w)*B + b)*BD + d]);
                }
                ulds[kl*16 + b] = v;
            }
            __syncthreads();
            if (comp) {
                float a0[16], a1[16];
                #pragma unroll
                for (int i = 0; i < 16; i++) { a0[i] = 0.f; a1[i] = 0.f; }
                #pragma unroll
                for (int g = 0; g < KPT; g++) {
                    int kb = (kq*KPT + g)*16;
                    float uu[16];
                    *(float4*)&uu[0]  = *(const float4*)&ulds[kb];
                    *(float4*)&uu[4]  = *(const float4*)&ulds[kb+4];
                    *(float4*)&uu[8]  = *(const float4*)&ulds[kb+8];
                    *(float4*)&uu[12] = *(const float4*)&ulds[kb+12];
                    float wa = w0[g], wb = w1r[g];
                    #pragma unroll
                    for (int bb = 0; bb < 16; bb++) {
                        a0[bb] = fmaf(wa, uu[bb], a0[bb]);
                        a1[bb] = fmaf(wb, uu[bb], a1[bb]);
                    }
                }
                #pragma unroll
                for (int bb = 0; bb < 16; bb++) {
                    red[kq*1024 + bb*64 + cp]      = a0[bb];
                    red[kq*1024 + bb*64 + cp + 32] = a1[bb];
                }
            }
            __syncthreads();
            int par = t & 3;
            for (int oi = tid; oi < 1024; oi += 512) {
                float sacc = 0.f;
                #pragma unroll
                for (int q = 0; q < 8; q++) sacc += red[q*1024 + oi];
                int bb = oi >> 6, cl = oi & 63;
                SCST(&ws[OFF_P + ((par*15 + kc)*B + bb)*832 + ct*64 + cl], sacc);
            }
            __syncthreads();   // drains vmcnt(0)
            if (tid == 0) SCST(&flg[FG_BULK + (t*15 + kc)*16 + ct], t + 1);
        }
    } else if (bid < NBULK + NFR) {
        // ================= FR (fresh + top-row + h1) =================
        int f = bid - NBULK;
        float* uL = (float*)smem;        // 336*16
        float* tL = uL + 5376;           // 336*16
        int c = tid & 63, bgrp = tid >> 6;
        int gcol = f*64 + c;
        bool isPQ = f < 4;
        bool valS = (!isPQ) && (gcol < 827);
        const float* wqp = wq + gcol;                       // + d*256
        const float* w1f = w1g + 336*BH + (gcol - 256);     // fresh S rows
        const float* w1t = w1g + (gcol - 256);              // top  S rows
        for (int t = 0; t < TDEC; t++) {
            if (t > 0) wait_words(flg + (t-1)*16, NU, tid);
            for (int e = tid; e < 5376; e += 512) {
                int b = e / 336, d = e - 336*b;
                uL[d*16 + b] = SCLD(&ws[OFF_U + ((t+16)*B + b)*BD + d]);
            }
            __syncthreads();
            float f0 = 0.f, f1 = 0.f;
            if (isPQ) {
                #pragma unroll 4
                for (int d = 0; d < BD; d++) {
                    float wv = wqp[d*HID];
                    f0 = fmaf(wv, uL[d*16 + bgrp], f0);
                    f1 = fmaf(wv, uL[d*16 + bgrp + 8], f1);
                }
                SCST(&ws[OFF_FPQ + bgrp*256 + gcol], f0);
                SCST(&ws[OFF_FPQ + (bgrp+8)*256 + gcol], f1);
                __syncthreads();
                if (tid == 0) SCST(&flg[FG_PQF + t*16 + f], t + 1);
            } else {
                if (valS) {
                    #pragma unroll 4
                    for (int d = 0; d < BD; d++) {
                        float wv = w1f[d*BH];
                        f0 = fmaf(wv, uL[d*16 + bgrp], f0);
                        f1 = fmaf(wv, uL[d*16 + bgrp + 8], f1);
                    }
                }
                // bulk-S partials for my col tile (15 kc words, ct == f)
                for (;;) {
                    int p = 1;
                    if (tid < 15) p = (__hip_atomic_load(
                        &flg[FG_BULK + (t*15 + tid)*16 + f], RLX, AGT) != 0);
                    if (__syncthreads_count(p) == 512) break;
                    __builtin_amdgcn_s_sleep(1);
                }
                int par = t & 3;
                float sb0 = 0.f, sb1 = 0.f;
                if (valS) {
                    #pragma unroll
                    for (int kc = 0; kc < 15; kc++) {
                        sb0 += SCLD(&ws[OFF_P + ((par*15+kc)*B + bgrp)*832 + gcol]);
                        sb1 += SCLD(&ws[OFF_P + ((par*15+kc)*B + bgrp+8)*832 + gcol]);
                    }
                    float bias = bp_b1[gcol - 256];
                    sb0 += bias; sb1 += bias;
                }
                wait_words(flg + FG_TOP + t*16, 16, tid);
                for (int e = tid; e < 5376; e += 512) {
                    int b = e / 336, d = e - 336*b;
                    tL[d*16 + b] = SCLD(&ws[OFF_TOP + b*BD + d]);
                }
                __syncthreads();
                if (valS) {
                    float t0a = 0.f, t1a = 0.f;
                    #pragma unroll 4
                    for (int d = 0; d < BD; d++) {
                        float wv = w1t[d*BH];
                        t0a = fmaf(wv, tL[d*16 + bgrp], t0a);
                        t1a = fmaf(wv, tL[d*16 + bgrp + 8], t1a);
                    }
                    SCST(&ws[OFF_H1 + bgrp*572 + (gcol-256)],
                         fmaxf(f0 + sb0 + t0a, 0.f));
                    SCST(&ws[OFF_H1 + (bgrp+8)*572 + (gcol-256)],
                         fmaxf(f1 + sb1 + t1a, 0.f));
                }
                __syncthreads();
                if (tid == 0) SCST(&flg[FG_H1 + t*16 + (f - 4)], t + 1);
            }
        }
    } else if (bid < NBULK + NFR + NU) {
        // ================= U (u = b2 + h1 @ w2T) =================
        int ub = bid - (NBULK + NFR);
        int dd0 = ub*24;
        float* h1L = (float*)smem;       // 16*576
        int ddl = tid & 31, b = tid >> 5;
        int dd = dd0 + ddl;
        bool act = (ddl < 24) && (dd < BD);
        for (int t = 0; t < TDEC; t++) {
            wait_words(flg + FG_H1 + t*16, 9, tid);
            for (int e = tid; e < 16*576; e += 512) {
                int bb = e / 576, cc = e - 576*bb;
                h1L[e] = (cc < BH) ? SCLD(&ws[OFF_H1 + bb*572 + cc]) : 0.f;
            }
            __syncthreads();
            if (act) {
                float acc = bp_b2[dd];
                const float4* wp = (const float4*)(ws + OFF_W2T + dd*572);
                const float4* hp = (const float4*)(h1L + b*576);
                #pragma unroll 4
                for (int q = 0; q < 143; q++) {
                    float4 w4 = wp[q], h4 = hp[q];
                    acc = fmaf(w4.x, h4.x, acc); acc = fmaf(w4.y, h4.y, acc);
                    acc = fmaf(w4.z, h4.z, acc); acc = fmaf(w4.w, h4.w, acc);
                }
                SCST(&ws[OFF_U + ((t + 17)*B + b)*BD + dd], acc);
            }
            __syncthreads();   // drains vmcnt(0)
            if (tid == 0) SCST(&flg[FG_CONS + t*16 + ub], t + 1);
        }
    } else {
        // ================= CONSUMER =================
        int b = bid - (NBULK + NFR + NU);
        float* pqa    = (float*)smem;            // 256
        float* pq2    = pqa + 256;               // 512
        float* sc     = pq2 + 512;               // 128
        float* attn_s = sc + 128;                // 128
        float* ctx2   = attn_s + 128;            // 512
        float* topv   = ctx2 + 512;              // 336
        float* avs    = topv + 336;              // 256
        if (tid < 256) avs[tid] = att_v[tid];
        for (int t = 0; t < TDEC; t++) {
            int par = t & 3;
            // wait for all bulk partials (195 words)
            for (;;) {
                int p = 1;
                if (tid < 195) {
                    int kc = tid / 13, ct = tid - 13*kc;
                    p = (__hip_atomic_load(
                        &flg[FG_BULK + (t*15 + kc)*16 + ct], RLX, AGT) != 0);
                }
                if (__syncthreads_count(p) == 512) break;
                __builtin_amdgcn_s_sleep(1);
            }
            {
                int col = tid & 255, hh = tid >> 8;
                float s_ = 0.f;
                int kA = hh*8, kB = hh ? 15 : 8;
                for (int kc = kA; kc < kB; kc++)
                    s_ += SCLD(&ws[OFF_P + ((par*15+kc)*B + b)*832 + col]);
                pq2[hh*256 + col] = s_;
            }
            wait_words(flg + FG_PQF + t*16, 4, tid);   // has barrier
            if (tid < 256)
                pqa[tid] = pq2[tid] + pq2[256+tid]
                         + SCLD(&ws[OFF_FPQ + b*256 + tid]) + att_bq[tid];
            __syncthreads();
            {   // scores
                int j = tid >> 2, hq = tid & 3;
                const float* par_ = ws + OFF_PA + (b*TENC + j)*HID + hq*64;
                const float* pqh = &pqa[hq*64];
                const float* avh = &avs[hq*64];
                float a = 0.f;
                #pragma unroll 8
                for (int h = 0; h < 64; h++) {
                    float x = pqh[h] + par_[h];
                    float e = __expf(2.f*x);
                    a += avh[h]*(1.f - 2.f/(e + 1.f));
                }
                a += __shfl_xor(a, 1);
                a += __shfl_xor(a, 2);
                if (hq == 0) sc[j] = a;
            }
            __syncthreads();
            if (tid < 64) {
                float s0 = sc[2*tid], s1 = sc[2*tid+1];
                float m = fmaxf(s0, s1);
                #pragma unroll
                for (int off = 1; off < 64; off <<= 1) m = fmaxf(m, __shfl_xor(m, off));
                float e0 = __expf(s0 - m), e1 = __expf(s1 - m);
                float ssum = e0 + e1;
                #pragma unroll
                for (int off = 1; off < 64; off <<= 1) ssum += __shfl_xor(ssum, off);
                float r = 1.f/ssum;
                attn_s[2*tid] = e0*r; attn_s[2*tid+1] = e1*r;
                attns[(b*TDEC + t)*TENC + 2*tid]   = e0*r;
                attns[(b*TDEC + t)*TENC + 2*tid+1] = e1*r;
            }
            __syncthreads();
            {   // ctx
                int i = tid & 255, jh = tid >> 8;
                const float* inp = inputs + (b*TENC + jh*64)*IND + i;
                float csum = 0.f;
                #pragma unroll 8
                for (int j = 0; j < 64; j++)
                    csum += attn_s[jh*64 + j]*inp[j*IND];
                ctx2[jh*256 + i] = csum;
            }
            __syncthreads();
            if (tid < 256) topv[tid] = ctx2[tid] + ctx2[256 + tid];
            else if (tid < BD) topv[tid] = ws[OFF_MEM + (t*B + b)*MD + (tid-256)];
            __syncthreads();
            if (tid < BD) SCST(&ws[OFF_TOP + b*BD + tid], topv[tid]);
            __syncthreads();   // drains vmcnt(0)
            if (tid == 0) SCST(&flg[FG_TOP + t*16 + b], t + 1);
        }
    }
}

// Epilogue: out[b,t,o] = c_out[o] + sum_{l,d} u_{t-l}[b][d]*M[l][d][o]
// grid 512 = 16 b x 4 t-quarters(25) x 8 o-tiles(50); u history in LDS.
__global__ __launch_bounds__(256) void k_q2(float* __restrict__ outs,
        const float* __restrict__ ws) {
    __shared__ __align__(16) float uL[41*340];
    int bid = blockIdx.x;
    int b = bid >> 5, r = bid & 31, th = r >> 3, oc = r & 7;
    int t0 = th*25, obase = oc*50;
    int tid = threadIdx.x;
    int s0 = t0 + 1;
    for (int idx = tid; idx < 41*336; idx += 256) {
        int rr = idx / 336, d = idx - 336*rr;
        uL[rr*340 + d] = ws[OFF_U + ((s0 + rr)*B + b)*BD + d];
    }
    __syncthreads();
    int o = tid % 50, tq = tid / 50;
    if (tq < 5) {
        float acc[5] = {0.f, 0.f, 0.f, 0.f, 0.f};
        for (int l = 0; l < LBUF; l++) {
            const float* Mp = ws + OFF_M + (l*BD)*OD + obase + o;
            const float* ub = &uL[(tq*5 + 16 - l)*340];
            for (int d4 = 0; d4 < 84; d4++) {
                int d = d4*4;
                float m0 = Mp[(d+0)*OD], m1 = Mp[(d+1)*OD];
                float m2 = Mp[(d+2)*OD], m3 = Mp[(d+3)*OD];
                #pragma unroll
                for (int i = 0; i < 5; i++) {
                    float4 u4 = *(const float4*)&ub[i*340 + d];
                    acc[i] = fmaf(u4.x, m0, acc[i]);
                    acc[i] = fmaf(u4.y, m1, acc[i]);
                    acc[i] = fmaf(u4.z, m2, acc[i]);
                    acc[i] = fmaf(u4.w, m3, acc[i]);
                }
            }
        }
        float co = ws[OFF_CO + obase + o];
        #pragma unroll
        for (int i = 0; i < 5; i++) {
            int t = t0 + tq*5 + i;
            outs[(b*TDEC + t)*OD + obase + o] = acc[i] + co;
        }
    }
}

extern "C" void kernel_launch(void* const* d_in, const int* in_sizes, int n_in,
                              void* d_out, int out_size, void* d_ws, size_t ws_size,
                              hipStream_t stream) {
    const float* inputs  = (const float*)d_in[0];
    const float* targets = (const float*)d_in[1];
    const float* mp_w1   = (const float*)d_in[2];
    const float* mp_b1   = (const float*)d_in[3];
    const float* mp_w2   = (const float*)d_in[4];
    const float* mp_b2   = (const float*)d_in[5];
    const float* bp_w1   = (const float*)d_in[6];
    const float* bp_b1   = (const float*)d_in[7];
    const float* bp_w2   = (const float*)d_in[8];
    const float* bp_b2   = (const float*)d_in[9];
    const float* att_wq  = (const float*)d_in[10];
    const float* att_bq  = (const float*)d_in[11];
    const float* att_wa  = (const float*)d_in[12];
    const float* att_ba  = (const float*)d_in[13];
    const float* att_v   = (const float*)d_in[14];
    const float* scale_w = (const float*)d_in[15];
    const float* scale_b = (const float*)d_in[16];
    const float* out_w   = (const float*)d_in[17];
    const float* out_b   = (const float*)d_in[18];
    float* ws = (float*)d_ws;
    float* outs = (float*)d_out;
    float* attns = outs + B*TDEC*OD;

    k_init<<<478, 256, 0, stream>>>(ws);
    k_pa  <<<B*TENC, 256, 0, stream>>>(inputs, att_wa, att_ba, ws);
    k_mem <<<TDEC*B, 128, 0, stream>>>(targets, mp_w1, mp_b1, mp_w2, mp_b2, ws);
    k_M   <<<17*14, 256, 0, stream>>>(scale_w, out_w, ws);
    k_cout<<<17, 256, 0, stream>>>(scale_b, out_w, out_b, ws);
    k_tr  <<<(BD*572 + 255)/256, 256, 0, stream>>>(bp_w2, ws);
    k_scan<<<NBLK, 512, 0, stream>>>(inputs, att_wq, bp_w1, att_bq, bp_b1,
                                     bp_b2, att_v, ws, attns);
    k_q2  <<<512, 256, 0, stream>>>(outs, ws);
}